// Round 1
// baseline (33852.725 us; speedup 1.0000x reference)
//
#include <hip/hip_runtime.h>
#include <hip/hip_bf16.h>
#include <cmath>

#define CDIV(a, b) (((a) + (b) - 1) / (b))

// ---------------------------------------------------------------------------
// Fusion: out = m * sepconv(feat, kv, kh) + (1-m) * feat
// sepconv: 5x5 separable per-pixel kernel, replicate padding.
// feat [B,C,H,W], kv/kh [B,5,H,W], m [B,1,H,W].
// ---------------------------------------------------------------------------
__global__ void fusion_kernel(const float* __restrict__ feat,
                              const float* __restrict__ kv,
                              const float* __restrict__ kh,
                              const float* __restrict__ m,
                              float* __restrict__ out,
                              int B, int C, int H, int W) {
    int idx = blockIdx.x * blockDim.x + threadIdx.x;
    int total = B * C * H * W;
    if (idx >= total) return;
    int x = idx % W;
    int y = (idx / W) % H;
    int c = (idx / (W * H)) % C;
    int b = idx / (W * H * C);

    int HW = H * W;
    const float* kvp = kv + (size_t)b * 5 * HW + y * W + x;
    const float* khp = kh + (size_t)b * 5 * HW + y * W + x;
    float kvv[5], khv[5];
#pragma unroll
    for (int i = 0; i < 5; ++i) {
        kvv[i] = kvp[(size_t)i * HW];
        khv[i] = khp[(size_t)i * HW];
    }
    int yy[5], xx[5];
#pragma unroll
    for (int i = 0; i < 5; ++i) {
        int t = y + i - 2;
        yy[i] = t < 0 ? 0 : (t >= H ? H - 1 : t);
        int u = x + i - 2;
        xx[i] = u < 0 ? 0 : (u >= W ? W - 1 : u);
    }
    const float* fp = feat + (size_t)(b * C + c) * HW;
    float acc = 0.f;
#pragma unroll
    for (int i = 0; i < 5; ++i) {
        const float* row = fp + (size_t)yy[i] * W;
        float r = 0.f;
#pragma unroll
        for (int j = 0; j < 5; ++j) r = fmaf(row[xx[j]], khv[j], r);
        acc = fmaf(kvv[i], r, acc);
    }
    float mv = m[(size_t)b * HW + y * W + x];
    float center = fp[(size_t)y * W + x];
    out[idx] = mv * acc + (1.f - mv) * center;
}

// ---------------------------------------------------------------------------
// ConvTranspose2d k=3 p=1 bias=False, gather formulation.
// out[b,co,y,x] = sum_{ci,i,j} in[b,ci,yi,xi] * w[ci,co,i,j]
//   where yi = (y+1-i)/STRIDE (valid iff divisible & in range), same for x.
// ACT: 0 = relu, 1 = tanh.
// ---------------------------------------------------------------------------
template <int STRIDE, int ACT>
__global__ void convt_kernel(const float* __restrict__ in,
                             const float* __restrict__ w,
                             float* __restrict__ out,
                             int B, int Cin, int Hin, int Win,
                             int Cout, int Hout, int Wout) {
    int idx = blockIdx.x * blockDim.x + threadIdx.x;
    int total = B * Cout * Hout * Wout;
    if (idx >= total) return;
    int x = idx % Wout;
    int y = (idx / Wout) % Hout;
    int co = (idx / (Wout * Hout)) % Cout;
    int b = idx / (Wout * Hout * Cout);

    int yis[3], wis[3], nyv = 0;
    int xis[3], wjs[3], nxv = 0;
#pragma unroll
    for (int i = 0; i < 3; ++i) {
        int t = y + 1 - i;
        if (STRIDE == 2 && (t & 1)) continue;
        int yi = t / STRIDE;
        if (yi < 0 || yi >= Hin) continue;
        yis[nyv] = yi; wis[nyv] = i; ++nyv;
    }
#pragma unroll
    for (int j = 0; j < 3; ++j) {
        int t = x + 1 - j;
        if (STRIDE == 2 && (t & 1)) continue;
        int xi = t / STRIDE;
        if (xi < 0 || xi >= Win) continue;
        xis[nxv] = xi; wjs[nxv] = j; ++nxv;
    }

    size_t HWin = (size_t)Hin * Win;
    const float* inb = in + (size_t)b * Cin * HWin;
    size_t C9 = (size_t)Cout * 9;
    float acc = 0.f;
    for (int a = 0; a < nyv; ++a) {
        for (int e = 0; e < nxv; ++e) {
            const float* ip = inb + (size_t)yis[a] * Win + xis[e];
            const float* wp = w + (size_t)co * 9 + wis[a] * 3 + wjs[e];
            int ci = 0;
            for (; ci + 4 <= Cin; ci += 4) {
                acc = fmaf(ip[(ci + 0) * HWin], wp[(ci + 0) * C9], acc);
                acc = fmaf(ip[(ci + 1) * HWin], wp[(ci + 1) * C9], acc);
                acc = fmaf(ip[(ci + 2) * HWin], wp[(ci + 2) * C9], acc);
                acc = fmaf(ip[(ci + 3) * HWin], wp[(ci + 3) * C9], acc);
            }
            for (; ci < Cin; ++ci)
                acc = fmaf(ip[ci * HWin], wp[ci * C9], acc);
        }
    }
    if (ACT == 0) {
        acc = acc > 0.f ? acc : 0.f;
    } else {
        acc = tanhf(acc);
    }
    out[idx] = acc;
}

// ---------------------------------------------------------------------------

static void launch_fusion(const float* feat, const float* kv, const float* kh,
                          const float* m, float* out, int B, int C, int H, int W,
                          hipStream_t s) {
    int total = B * C * H * W;
    fusion_kernel<<<CDIV(total, 256), 256, 0, s>>>(feat, kv, kh, m, out, B, C, H, W);
}

template <int STRIDE, int ACT>
static void launch_convt(const float* in, const float* w, float* out,
                         int B, int Cin, int Hin, int Win, int Cout,
                         hipStream_t s) {
    int Hout = (STRIDE == 2) ? 2 * Hin : Hin;
    int Wout = (STRIDE == 2) ? 2 * Win : Win;
    int total = B * Cout * Hout * Wout;
    convt_kernel<STRIDE, ACT><<<CDIV(total, 256), 256, 0, s>>>(
        in, w, out, B, Cin, Hin, Win, Cout, Hout, Wout);
}

extern "C" void kernel_launch(void* const* d_in, const int* in_sizes, int n_in,
                              void* d_out, int out_size, void* d_ws, size_t ws_size,
                              hipStream_t stream) {
    const float* cont = (const float*)d_in[0];
    const float* w1 = (const float*)d_in[1];
    const float* w2 = (const float*)d_in[2];
    const float* w3 = (const float*)d_in[3];
    const float* w4 = (const float*)d_in[4];
    const float* w5 = (const float*)d_in[5];
    const float* w6 = (const float*)d_in[6];
    const float* kv0 = (const float*)d_in[7];
    const float* kh0 = (const float*)d_in[8];
    const float* m0 = (const float*)d_in[9];
    const float* kv1 = (const float*)d_in[10];
    const float* kh1 = (const float*)d_in[11];
    const float* m1 = (const float*)d_in[12];
    const float* kv2 = (const float*)d_in[13];
    const float* kh2 = (const float*)d_in[14];
    const float* m2 = (const float*)d_in[15];
    const float* kv3 = (const float*)d_in[16];
    const float* kh3 = (const float*)d_in[17];
    const float* m3 = (const float*)d_in[18];

    float* out = (float*)d_out;
    const int B = 32;
    // d_out layout: [out 32*3*128*128][f8 32*64*16*16][f16 32*512*32*32][f32 32*128*64*64]
    float* OUT0 = out;
    float* F8 = out + 1572864;
    float* F16 = out + 2097152;
    float* F32 = out + 18874368;

    // scratch: two ping-pong regions of 16,777,216 floats (64 MiB) each
    float* A = (float*)d_ws;
    float* Bw = A + 16777216;

    // 1. f8 = fusion(cont_feat)                       [32,64,16,16]
    launch_fusion(cont, kv0, kh0, m0, F8, B, 64, 16, 16, stream);
    // 2. t16 = relu(convT(f8, w1, s2, op1))           [32,512,32,32] -> A
    launch_convt<2, 0>(F8, w1, A, B, 64, 16, 16, 512, stream);
    // 3. f16 = fusion(t16)                            -> d_out
    launch_fusion(A, kv1, kh1, m1, F16, B, 512, 32, 32, stream);
    // 4. t32a = relu(convT(f16, w2, s1))              [32,256,32,32] -> A
    launch_convt<1, 0>(F16, w2, A, B, 512, 32, 32, 256, stream);
    // 5. t32b = relu(convT(t32a, w3, s2, op1))        [32,128,64,64] -> B
    launch_convt<2, 0>(A, w3, Bw, B, 256, 32, 32, 128, stream);
    // 6. f32 = fusion(t32b)                           -> d_out
    launch_fusion(Bw, kv2, kh2, m2, F32, B, 128, 64, 64, stream);
    // 7. t64a = relu(convT(f32, w4, s1))              [32,128,64,64] -> A
    launch_convt<1, 0>(F32, w4, A, B, 128, 64, 64, 128, stream);
    // 8. t64b = relu(convT(t64a, w5, s2, op1))        [32,64,128,128] -> B
    launch_convt<2, 0>(A, w5, Bw, B, 128, 64, 64, 64, stream);
    // 9. t_out = tanh(convT(t64b, w6, s1))            [32,3,128,128] -> A
    launch_convt<1, 1>(Bw, w6, A, B, 64, 128, 128, 3, stream);
    // 10. out = fusion(t_out)                         -> d_out
    launch_fusion(A, kv3, kh3, m3, OUT0, B, 3, 128, 128, stream);
}

// Round 2
// 1132.431 us; speedup vs baseline: 29.8939x; 29.8939x over previous
//
#include <hip/hip_runtime.h>
#include <hip/hip_bf16.h>
#include <cmath>

#define CDIV(a, b) (((a) + (b) - 1) / (b))

typedef __attribute__((ext_vector_type(8))) short bf16x8;
typedef __attribute__((ext_vector_type(4))) float f32x4;

__device__ __forceinline__ short f2bf(float f) {
    unsigned u = __float_as_uint(f);
    unsigned r = (u + 0x7fff + ((u >> 16) & 1)) >> 16;
    return (short)r;
}

__device__ __forceinline__ void gll16(const void* g, void* l) {
    __builtin_amdgcn_global_load_lds((const __attribute__((address_space(1))) void*)g,
                                     (__attribute__((address_space(3))) void*)l, 16, 0, 0);
}

// ---------------------------------------------------------------------------
// Fusion (unchanged from round 1, fp32, memory-bound)
// ---------------------------------------------------------------------------
__global__ void fusion_kernel(const float* __restrict__ feat,
                              const float* __restrict__ kv,
                              const float* __restrict__ kh,
                              const float* __restrict__ m,
                              float* __restrict__ out,
                              int B, int C, int H, int W) {
    int idx = blockIdx.x * blockDim.x + threadIdx.x;
    int total = B * C * H * W;
    if (idx >= total) return;
    int x = idx % W;
    int y = (idx / W) % H;
    int c = (idx / (W * H)) % C;
    int b = idx / (W * H * C);

    int HW = H * W;
    const float* kvp = kv + (size_t)b * 5 * HW + y * W + x;
    const float* khp = kh + (size_t)b * 5 * HW + y * W + x;
    float kvv[5], khv[5];
#pragma unroll
    for (int i = 0; i < 5; ++i) {
        kvv[i] = kvp[(size_t)i * HW];
        khv[i] = khp[(size_t)i * HW];
    }
    int yy[5], xx[5];
#pragma unroll
    for (int i = 0; i < 5; ++i) {
        int t = y + i - 2;
        yy[i] = t < 0 ? 0 : (t >= H ? H - 1 : t);
        int u = x + i - 2;
        xx[i] = u < 0 ? 0 : (u >= W ? W - 1 : u);
    }
    const float* fp = feat + (size_t)(b * C + c) * HW;
    float acc = 0.f;
#pragma unroll
    for (int i = 0; i < 5; ++i) {
        const float* row = fp + (size_t)yy[i] * W;
        float r = 0.f;
#pragma unroll
        for (int j = 0; j < 5; ++j) r = fmaf(row[xx[j]], khv[j], r);
        acc = fmaf(kvv[i], r, acc);
    }
    float mv = m[(size_t)b * HW + y * W + x];
    float center = fp[(size_t)y * W + x];
    out[idx] = mv * acc + (1.f - mv) * center;
}

// ---------------------------------------------------------------------------
// Pad pass: fp32 NCHW -> bf16 NHWC with convT's lhs-dilation + (1, 1+op) pad.
// pin[b][yp][xp][c], Hp = Hout+2. Thread writes 8 contiguous channels (16B).
// ---------------------------------------------------------------------------
template <int STRIDE>
__global__ void pad_kernel(const float* __restrict__ in, short* __restrict__ pin,
                           int Bc, int C, int H, int W, int Hp, int Wp, int total) {
    int tid = blockIdx.x * blockDim.x + threadIdx.x;
    if (tid >= total) return;
    int C8 = C >> 3;
    int c8 = tid % C8;
    int xp = (tid / C8) % Wp;
    int yp = (tid / (C8 * Wp)) % Hp;
    int b = tid / (C8 * Wp * Hp);

    int y, x;
    bool valid;
    if (STRIDE == 1) {
        y = yp - 1; x = xp - 1;
        valid = (y >= 0 && y < H && x >= 0 && x < W);
    } else {
        int dy = yp - 1, dx = xp - 1;
        valid = (dy >= 0 && dx >= 0 && !(dy & 1) && !(dx & 1));
        y = dy >> 1; x = dx >> 1;
        valid = valid && (y < H) && (x < W);
    }
    bf16x8 v;
    if (valid) {
        const float* ip = in + ((size_t)(b * C + c8 * 8) * H + y) * W + x;
        size_t HW = (size_t)H * W;
#pragma unroll
        for (int k = 0; k < 8; ++k) v[k] = f2bf(ip[k * HW]);
    } else {
        v = (bf16x8)0;
    }
    *(bf16x8*)(pin + (size_t)tid * 8) = v;
}

// ---------------------------------------------------------------------------
// Weight transform: wt[tap][m][ci] = bf16(w[ci][m][2-i][2-j]), m padded to Mp.
// ---------------------------------------------------------------------------
__global__ void wtrans_kernel(const float* __restrict__ w, short* __restrict__ wt,
                              int Cin, int Cout, int Mp, int total) {
    int tid = blockIdx.x * blockDim.x + threadIdx.x;
    if (tid >= total) return;
    int ci = tid % Cin;
    int mm = (tid / Cin) % Mp;
    int tap = tid / (Cin * Mp);
    int i = tap / 3, j = tap % 3;
    float v = 0.f;
    if (mm < Cout) v = w[((ci * Cout + mm) * 3 + (2 - i)) * 3 + (2 - j)];
    wt[tid] = f2bf(v);
}

// ---------------------------------------------------------------------------
// Implicit-GEMM convT: out[b,co,y,x] = sum_{tap,ci} pin[b,y+i,x+j,ci]*wt[tap,co,ci]
// Tile: BM x 64 pixels, BK=64, 4 waves (2M x 2N). 16x16x32 bf16 MFMA.
// LDS rows 128B, XOR swizzle chunk^=(row&7) -> conflict-free ds_read_b128.
// ---------------------------------------------------------------------------
template <int BM, int ACT>
__global__ void convt_mfma(const short* __restrict__ pin, const short* __restrict__ wt,
                           float* __restrict__ out,
                           int Hp, int Wp, int Cin, int Mp, int Cout, int Ho, int Wo) {
    constexpr int WM = BM / 2;       // 32 or 64
    constexpr int FM = WM / 16;      // 2 or 4
    constexpr int AROUNDS = BM / 32; // 2 or 4
    __shared__ __align__(16) short Alds[BM * 64];
    __shared__ __align__(16) short Blds[64 * 64];

    int t = threadIdx.x;
    int lane = t & 63, wid = t >> 6;
    int m0 = blockIdx.y * BM;
    int n0 = blockIdx.x * 64;

    // ---- staging geometry (per-thread, constant over K loop)
    int rowS = t >> 3;              // 0..31 within a 4KB round
    int pS = t & 7;                 // LDS chunk position within 128B row
    int dS = pS ^ (rowS & 7);       // global data chunk (inverse swizzle)
    int HoWo = Ho * Wo;

    int n_r0 = n0 + rowS;
    int n_r1 = n0 + rowS + 32;
    int b0p = n_r0 / HoWo, rr0 = n_r0 % HoWo;
    int b1p = n_r1 / HoWo, rr1 = n_r1 % HoWo;
    int pxoff0 = ((b0p * Hp + rr0 / Wo) * Wp + rr0 % Wo) * Cin + dS * 8;
    int pxoff1 = ((b1p * Hp + rr1 / Wo) * Wp + rr1 % Wo) * Cin + dS * 8;
    int aoffg = (m0 + rowS) * Cin + dS * 8;

    char* AldsB = (char*)Alds;
    char* BldsB = (char*)Blds;
    char* aW = AldsB + (wid << 10);
    char* bW = BldsB + (wid << 10);

    // ---- fragment read offsets
    int wm = wid & 1, wn = wid >> 1;
    int cb = lane >> 4;  // 0..3
    int rm[FM], rn[2];
#pragma unroll
    for (int mf = 0; mf < FM; ++mf) rm[mf] = wm * WM + mf * 16 + (lane & 15);
#pragma unroll
    for (int nf = 0; nf < 2; ++nf) rn[nf] = wn * 32 + nf * 16 + (lane & 15);

    f32x4 acc[FM][2];
#pragma unroll
    for (int mf = 0; mf < FM; ++mf)
#pragma unroll
        for (int nf = 0; nf < 2; ++nf) acc[mf][nf] = (f32x4){0.f, 0.f, 0.f, 0.f};

    int KC = Cin >> 6;
    for (int tap = 0; tap < 9; ++tap) {
        int ti = tap / 3, tj = tap % 3;
        int tpix = (ti * Wp + tj) * Cin;
        int wtap = tap * Mp * Cin;
        for (int cc = 0; cc < KC; ++cc) {
            int cbase = cc * 64;
            __syncthreads();  // previous compute done before overwrite
#pragma unroll
            for (int r = 0; r < AROUNDS; ++r)
                gll16(wt + wtap + cbase + aoffg + r * 32 * Cin, aW + r * 4096);
            gll16(pin + tpix + cbase + pxoff0, bW);
            gll16(pin + tpix + cbase + pxoff1, bW + 4096);
            __syncthreads();  // drains vmcnt -> tiles visible to all waves
#pragma unroll
            for (int h = 0; h < 2; ++h) {
                bf16x8 av[FM], bv[2];
#pragma unroll
                for (int mf = 0; mf < FM; ++mf)
                    av[mf] = *(const bf16x8*)(AldsB + rm[mf] * 128 +
                                              (((h * 4 + cb) ^ (rm[mf] & 7)) << 4));
#pragma unroll
                for (int nf = 0; nf < 2; ++nf)
                    bv[nf] = *(const bf16x8*)(BldsB + rn[nf] * 128 +
                                              (((h * 4 + cb) ^ (rn[nf] & 7)) << 4));
#pragma unroll
                for (int mf = 0; mf < FM; ++mf)
#pragma unroll
                    for (int nf = 0; nf < 2; ++nf)
                        acc[mf][nf] = __builtin_amdgcn_mfma_f32_16x16x32_bf16(
                            av[mf], bv[nf], acc[mf][nf], 0, 0, 0);
            }
        }
    }

    // ---- epilogue: D row (co) = (lane>>4)*4 + reg, col (pixel) = lane&15
#pragma unroll
    for (int mf = 0; mf < FM; ++mf) {
#pragma unroll
        for (int nf = 0; nf < 2; ++nf) {
            int cobase = m0 + wm * WM + mf * 16 + (lane >> 4) * 4;
            int px = n0 + wn * 32 + nf * 16 + (lane & 15);
            int b = px / HoWo;
            int rr = px % HoWo;
            int y = rr / Wo, x = rr % Wo;
            f32x4 v = acc[mf][nf];
#pragma unroll
            for (int reg = 0; reg < 4; ++reg) {
                int co = cobase + reg;
                if (co < Cout) {
                    float f = v[reg];
                    if (ACT == 0) f = f > 0.f ? f : 0.f;
                    else f = tanhf(f);
                    out[((b * Cout + co) * Ho + y) * Wo + x] = f;
                }
            }
        }
    }
}

// ---------------------------------------------------------------------------

static void launch_fusion(const float* feat, const float* kv, const float* kh,
                          const float* m, float* out, int B, int C, int H, int W,
                          hipStream_t s) {
    int total = B * C * H * W;
    fusion_kernel<<<CDIV(total, 256), 256, 0, s>>>(feat, kv, kh, m, out, B, C, H, W);
}

static void launch_pad(int stride, const float* in, short* pin, int Bc, int C, int H,
                       int W, hipStream_t s) {
    int Hp = (stride == 1) ? H + 2 : 2 * H + 2;
    int Wp = (stride == 1) ? W + 2 : 2 * W + 2;
    int total = Bc * Hp * Wp * (C / 8);
    if (stride == 1)
        pad_kernel<1><<<CDIV(total, 256), 256, 0, s>>>(in, pin, Bc, C, H, W, Hp, Wp, total);
    else
        pad_kernel<2><<<CDIV(total, 256), 256, 0, s>>>(in, pin, Bc, C, H, W, Hp, Wp, total);
}

static void launch_conv(int act, const short* pin, const short* wt, float* out,
                        int Bc, int Cin, int Mp, int Cout, int Ho, int Wo,
                        hipStream_t s) {
    int Hp = Ho + 2, Wp = Wo + 2;
    dim3 grid(Bc * Ho * Wo / 64, Mp >= 128 ? Mp / 128 : 1);
    if (Mp >= 128) {
        if (act == 0)
            convt_mfma<128, 0><<<grid, 256, 0, s>>>(pin, wt, out, Hp, Wp, Cin, Mp, Cout, Ho, Wo);
        else
            convt_mfma<128, 1><<<grid, 256, 0, s>>>(pin, wt, out, Hp, Wp, Cin, Mp, Cout, Ho, Wo);
    } else {
        grid.y = Mp / 64;
        if (act == 0)
            convt_mfma<64, 0><<<grid, 256, 0, s>>>(pin, wt, out, Hp, Wp, Cin, Mp, Cout, Ho, Wo);
        else
            convt_mfma<64, 1><<<grid, 256, 0, s>>>(pin, wt, out, Hp, Wp, Cin, Mp, Cout, Ho, Wo);
    }
}

extern "C" void kernel_launch(void* const* d_in, const int* in_sizes, int n_in,
                              void* d_out, int out_size, void* d_ws, size_t ws_size,
                              hipStream_t stream) {
    const float* cont = (const float*)d_in[0];
    const float* w1 = (const float*)d_in[1];
    const float* w2 = (const float*)d_in[2];
    const float* w3 = (const float*)d_in[3];
    const float* w4 = (const float*)d_in[4];
    const float* w5 = (const float*)d_in[5];
    const float* w6 = (const float*)d_in[6];
    const float* kv0 = (const float*)d_in[7];
    const float* kh0 = (const float*)d_in[8];
    const float* m0 = (const float*)d_in[9];
    const float* kv1 = (const float*)d_in[10];
    const float* kh1 = (const float*)d_in[11];
    const float* m1 = (const float*)d_in[12];
    const float* kv2 = (const float*)d_in[13];
    const float* kh2 = (const float*)d_in[14];
    const float* m2 = (const float*)d_in[15];
    const float* kv3 = (const float*)d_in[16];
    const float* kh3 = (const float*)d_in[17];
    const float* m3 = (const float*)d_in[18];

    float* out = (float*)d_out;
    float* OUT0 = out;
    float* F8 = out + 1572864;
    float* F16 = out + 2097152;
    float* F32 = out + 18874368;

    float* ws = (float*)d_ws;
    // ws layout (floats): [WT 1M][PIN 10M][T 16.78M][U 4.2M][TOUTC 0.2M] = 130.8MB
    short* WTb = (short*)ws;                       // capacity 2M bf16
    short* PINb = (short*)(ws + 1048576);          // capacity 20.97M bf16
    float* T = ws + 11534336;                      // 16,777,216 floats
    float* U = ws + 28311552;                      // 4,194,304 floats (t64b chunk)
    float* TOUTC = ws + 32505856;                  // 196,608 floats (t_out chunk)

    short* wt1 = WTb;
    short* wt2 = WTb + 294912;
    short* wt3 = WTb + 1474560;
    short* wt4 = WTb + 1769472;
    short* wt5 = WTb + 1916928;
    short* wt6 = WTb + 1990656;

    // weight transforms (tiny)
    auto wtr = [&](const float* w, short* wt, int Cin, int Cout, int Mp) {
        int total = 9 * Mp * Cin;
        wtrans_kernel<<<CDIV(total, 256), 256, 0, stream>>>(w, wt, Cin, Cout, Mp, total);
    };
    wtr(w1, wt1, 64, 512, 512);
    wtr(w2, wt2, 512, 256, 256);
    wtr(w3, wt3, 256, 128, 128);
    wtr(w4, wt4, 128, 128, 128);
    wtr(w5, wt5, 128, 64, 64);
    wtr(w6, wt6, 64, 3, 64);

    // 1. f8 = fusion(cont_feat) [32,64,16,16]
    launch_fusion(cont, kv0, kh0, m0, F8, 32, 64, 16, 16, stream);
    // 2. t16 = relu(convT(f8, w1, s2)) [32,512,32,32] -> T
    launch_pad(2, F8, PINb, 32, 64, 16, 16, stream);
    launch_conv(0, PINb, wt1, T, 32, 64, 512, 512, 32, 32, stream);
    // 3. f16 = fusion(t16) -> d_out
    launch_fusion(T, kv1, kh1, m1, F16, 32, 512, 32, 32, stream);
    // 4. t32a = relu(convT(f16, w2, s1)) [32,256,32,32] -> F32 region (scratch)
    launch_pad(1, F16, PINb, 32, 512, 32, 32, stream);
    launch_conv(0, PINb, wt2, F32, 32, 512, 256, 256, 32, 32, stream);
    // 5. t32b = relu(convT(t32a, w3, s2)) [32,128,64,64] -> T (2 batch-chunks)
    for (int h2 = 0; h2 < 2; ++h2) {
        const float* src = F32 + (size_t)h2 * 16 * 256 * 1024;
        launch_pad(2, src, PINb, 16, 256, 32, 32, stream);
        launch_conv(0, PINb, wt3, T + (size_t)h2 * 16 * 128 * 4096, 16, 256, 128, 128,
                    64, 64, stream);
    }
    // 6. f32 = fusion(t32b) -> d_out (overwrites t32a scratch, already consumed)
    launch_fusion(T, kv2, kh2, m2, F32, 32, 128, 64, 64, stream);
    // 7. t64a = relu(convT(f32, w4, s1)) [32,128,64,64] -> T
    launch_pad(1, F32, PINb, 32, 128, 64, 64, stream);
    launch_conv(0, PINb, wt4, T, 32, 128, 128, 128, 64, 64, stream);
    // 8-10. conv5 -> conv6 -> fusion3, in 8 batch-chunks of 4
    short* pin6c = PINb + 10485760;
    for (int q = 0; q < 8; ++q) {
        const float* s5 = T + (size_t)q * 4 * 128 * 4096;
        launch_pad(2, s5, PINb, 4, 128, 64, 64, stream);
        launch_conv(0, PINb, wt5, U, 4, 128, 64, 64, 128, 128, stream);
        launch_pad(1, U, pin6c, 4, 64, 128, 128, stream);
        launch_conv(1, pin6c, wt6, TOUTC, 4, 64, 64, 3, 128, 128, stream);
        int boff = q * 4;
        launch_fusion(TOUTC, kv3 + (size_t)boff * 5 * 16384, kh3 + (size_t)boff * 5 * 16384,
                      m3 + (size_t)boff * 16384, OUT0 + (size_t)boff * 3 * 16384,
                      4, 3, 128, 128, stream);
    }
}

// Round 3
// 738.786 us; speedup vs baseline: 45.8221x; 1.5328x over previous
//
#include <hip/hip_runtime.h>
#include <hip/hip_bf16.h>
#include <cmath>

#define CDIV(a, b) (((a) + (b) - 1) / (b))

typedef __attribute__((ext_vector_type(8))) short bf16x8;
typedef __attribute__((ext_vector_type(4))) short s16x4;
typedef __attribute__((ext_vector_type(4))) float f32x4;

__device__ __forceinline__ short f2bf(float f) {
    unsigned u = __float_as_uint(f);
    unsigned r = (u + 0x7fff + ((u >> 16) & 1)) >> 16;
    return (short)r;
}

__device__ __forceinline__ void gll16(const void* g, void* l) {
    __builtin_amdgcn_global_load_lds((const __attribute__((address_space(1))) void*)g,
                                     (__attribute__((address_space(3))) void*)l, 16, 0, 0);
}

// ---------------------------------------------------------------------------
// Vectorized fusion: 4 consecutive x per thread. out = m*sepconv + (1-m)*feat
// ---------------------------------------------------------------------------
__global__ void fusion4_kernel(const float* __restrict__ feat,
                               const float* __restrict__ kv,
                               const float* __restrict__ kh,
                               const float* __restrict__ m,
                               float* __restrict__ out,
                               int B, int C, int H, int W, int total) {
    int idx = blockIdx.x * blockDim.x + threadIdx.x;
    if (idx >= total) return;
    int Wg = W >> 2;
    int g = idx % Wg;
    int y = (idx / Wg) % H;
    int c = (idx / (Wg * H)) % C;
    int b = idx / (Wg * H * C);
    int x0 = g << 2;
    int HW = H * W;

    const float* fp = feat + (size_t)(b * C + c) * HW;
    int yy[5];
#pragma unroll
    for (int i = 0; i < 5; ++i) {
        int t = y + i - 2;
        yy[i] = t < 0 ? 0 : (t >= H ? H - 1 : t);
    }
    const float* kvb = kv + ((size_t)b * 5 * H + y) * W + x0;
    const float* khb = kh + ((size_t)b * 5 * H + y) * W + x0;

    f32x4 res;
    if (g >= 1 && g <= Wg - 2) {
        f32x4 kvv[5], khv[5];
#pragma unroll
        for (int i = 0; i < 5; ++i) {
            kvv[i] = *(const f32x4*)(kvb + (size_t)i * HW);
            khv[i] = *(const f32x4*)(khb + (size_t)i * HW);
        }
        f32x4 acc = (f32x4){0.f, 0.f, 0.f, 0.f};
#pragma unroll
        for (int i = 0; i < 5; ++i) {
            const float* row = fp + (size_t)yy[i] * W + x0;
            f32x4 Lv = *(const f32x4*)(row - 4);
            f32x4 Cv = *(const f32x4*)(row);
            f32x4 Rv = *(const f32x4*)(row + 4);
            float w8[8] = {Lv[2], Lv[3], Cv[0], Cv[1], Cv[2], Cv[3], Rv[0], Rv[1]};
#pragma unroll
            for (int o = 0; o < 4; ++o) {
                float r = 0.f;
#pragma unroll
                for (int j = 0; j < 5; ++j) r = fmaf(khv[j][o], w8[o + j], r);
                acc[o] = fmaf(kvv[i][o], r, acc[o]);
            }
        }
        res = acc;
    } else {
        // border group: scalar with x-clamp
#pragma unroll
        for (int o = 0; o < 4; ++o) {
            int x = x0 + o;
            int xx[5];
#pragma unroll
            for (int j = 0; j < 5; ++j) {
                int u = x + j - 2;
                xx[j] = u < 0 ? 0 : (u >= W ? W - 1 : u);
            }
            float acc = 0.f;
#pragma unroll
            for (int i = 0; i < 5; ++i) {
                const float* row = fp + (size_t)yy[i] * W;
                float kvs = kvb[(size_t)i * HW + o - 0] ; // kvb already at x0; +o
                kvs = kvb[(size_t)i * HW + o];
                float r = 0.f;
#pragma unroll
                for (int j = 0; j < 5; ++j) r = fmaf(khb[(size_t)j * HW + o], row[xx[j]], r);
                acc = fmaf(kvs, r, acc);
            }
            res[o] = acc;
        }
    }
    const float* mp = m + ((size_t)b * H + y) * W + x0;
    f32x4 m4 = *(const f32x4*)mp;
    f32x4 c4 = *(const f32x4*)(fp + (size_t)y * W + x0);
    f32x4 o4;
#pragma unroll
    for (int o = 0; o < 4; ++o) o4[o] = m4[o] * res[o] + (1.f - m4[o]) * c4[o];
    *(f32x4*)(out + ((size_t)(b * C + c) * H + y) * W + x0) = o4;
}

// ---------------------------------------------------------------------------
// Pads: fp32 NCHW -> bf16 NHWC. s1: (H+2)x(W+2) 1-pad all around.
//                               s2: (H+1)x(W+1) zero-pad high only (no dilation).
// ---------------------------------------------------------------------------
template <int STRIDE>
__global__ void pad_kernel(const float* __restrict__ in, short* __restrict__ pin,
                           int C, int H, int W, int Hp, int Wp, int total) {
    int tid = blockIdx.x * blockDim.x + threadIdx.x;
    if (tid >= total) return;
    int C8 = C >> 3;
    int c8 = tid % C8;
    int xp = (tid / C8) % Wp;
    int yp = (tid / (C8 * Wp)) % Hp;
    int b = tid / (C8 * Wp * Hp);

    int y, x;
    bool valid;
    if (STRIDE == 1) {
        y = yp - 1; x = xp - 1;
        valid = (y >= 0 && y < H && x >= 0 && x < W);
    } else {
        y = yp; x = xp;
        valid = (y < H && x < W);
    }
    bf16x8 v;
    if (valid) {
        const float* ip = in + ((size_t)(b * C + c8 * 8) * H + y) * W + x;
        size_t HW = (size_t)H * W;
#pragma unroll
        for (int k = 0; k < 8; ++k) v[k] = f2bf(ip[k * HW]);
    } else {
        v = (bf16x8)0;
    }
    *(bf16x8*)(pin + (size_t)tid * 8) = v;
}

// zero the pad borders of an NHWC bf16 pin buffer written by a conv epilogue
__global__ void zb_kernel(short* __restrict__ buf, int Hp, int Wp, int C8, int mode,
                          int total) {
    int tid = blockIdx.x * blockDim.x + threadIdx.x;
    if (tid >= total) return;
    int xp = (tid / C8) % Wp;
    int yp = (tid / (C8 * Wp)) % Hp;
    bool border = mode ? (yp == 0 || yp == Hp - 1 || xp == 0 || xp == Wp - 1)
                       : (yp == Hp - 1 || xp == Wp - 1);
    if (border) *(bf16x8*)(buf + (size_t)tid * 8) = (bf16x8)0;
}

// ---------------------------------------------------------------------------
// Weight transform. Packs per-phase tap blocks: wt[t9][m][ci].
// s1: t9=(a,b) 3x3, i=2-a, j=2-b.  s2: phases (0,0),(0,1),(1,0),(1,1) sizes
// {1,2,2,4}; y-taps for py=0: [(dy0,i1)]; py=1: [(dy0,i2),(dy1,i0)]; x same.
// ---------------------------------------------------------------------------
__global__ void wtrans_kernel(const float* __restrict__ w, short* __restrict__ wt,
                              int Cin, int Cout, int Mp, int stride, int total) {
    int tid = blockIdx.x * blockDim.x + threadIdx.x;
    if (tid >= total) return;
    int ci = tid % Cin;
    int mm = (tid / Cin) % Mp;
    int t9 = tid / (Cin * Mp);
    int i, j;
    if (stride == 1) {
        int a = t9 / 3, bb = t9 % 3;
        i = 2 - a; j = 2 - bb;
    } else {
        int py, px, a, bb;
        if (t9 == 0) { py = 0; px = 0; a = 0; bb = 0; }
        else if (t9 < 3) { py = 0; px = 1; a = 0; bb = t9 - 1; }
        else if (t9 < 5) { py = 1; px = 0; a = t9 - 3; bb = 0; }
        else { int tt = t9 - 5; py = 1; px = 1; a = tt >> 1; bb = tt & 1; }
        i = (py == 0) ? 1 : (a == 0 ? 2 : 0);
        j = (px == 0) ? 1 : (bb == 0 ? 2 : 0);
    }
    float v = 0.f;
    if (mm < Cout) v = w[((ci * Cout + mm) * 3 + i) * 3 + j];
    wt[tid] = f2bf(v);
}

// ---------------------------------------------------------------------------
// Implicit-GEMM convT with phase decomposition.
// S2: blockIdx.z = phase (py,px); K-taps = (1+py)*(1+px).  S1: 9 taps.
// OUTM 0: fp32 NCHW (+ACT relu/tanh). OUTM 1: bf16 NHWC padded pin (relu).
// ---------------------------------------------------------------------------
template <int BM, bool S2, int OUTM, int ACT>
__global__ void convt_mfma(const short* __restrict__ pin, const short* __restrict__ wtc,
                           float* __restrict__ outf, short* __restrict__ outb,
                           int Hpin, int Wpin, int Cin, int Mp, int Cout,
                           int Ho, int Wo, int Hu, int Wv,
                           int Hop, int Wop, int poff) {
    constexpr int WM = (BM == 16) ? 16 : BM / 2;
    constexpr int FM = WM / 16;
    constexpr int FN = (BM == 16) ? 1 : 2;
    constexpr int NSPAN = (BM == 16) ? 16 : 32;
    __shared__ __align__(16) short Alds[BM * 64];
    __shared__ __align__(16) short Blds[64 * 64];

    int t = threadIdx.x, lane = t & 63, wid = t >> 6;
    int n0 = blockIdx.x * 64, m0 = blockIdx.y * BM;

    int py = 0, px = 0, ny = 3, nx = 3, dys = 0x210, dxs = 0x210, sy = 1;
    const short* wt = wtc;
    if (S2) {
        int pz = blockIdx.z;
        py = pz >> 1; px = pz & 1;
        ny = 1 + py; nx = 1 + px;
        dys = py ? 0x10 : 0; dxs = px ? 0x10 : 0;
        int pre = (pz == 0) ? 0 : (pz == 1) ? 1 : (pz == 2) ? 3 : 5;
        wt = wtc + (size_t)pre * Mp * Cin;
        sy = 2;
    }

    // staging geometry
    int rowS = t >> 3;
    int dS = (t & 7) ^ (rowS & 7);
    int HuWv = Hu * Wv;
    int pxg[2];
#pragma unroll
    for (int rb = 0; rb < 2; ++rb) {
        int n = n0 + rowS + rb * 32;
        int b = n / HuWv, r = n % HuWv;
        int u = r / Wv, v = r % Wv;
        pxg[rb] = ((b * Hpin + u) * Wpin + v) * Cin + dS * 8;
    }
    int aoff = (m0 + rowS) * Cin + dS * 8;

    char* AB = (char*)Alds;
    char* BB = (char*)Blds;

    int wm = (BM == 16) ? 0 : (wid & 1);
    int wn = (BM == 16) ? wid : (wid >> 1);
    int cb = lane >> 4;
    int rm[FM], rn[FN];
#pragma unroll
    for (int mf = 0; mf < FM; ++mf) rm[mf] = wm * WM + mf * 16 + (lane & 15);
#pragma unroll
    for (int nf = 0; nf < FN; ++nf) rn[nf] = wn * NSPAN + nf * 16 + (lane & 15);

    f32x4 acc[FM][FN];
#pragma unroll
    for (int mf = 0; mf < FM; ++mf)
#pragma unroll
        for (int nf = 0; nf < FN; ++nf) acc[mf][nf] = (f32x4){0.f, 0.f, 0.f, 0.f};

    for (int a = 0; a < ny; ++a) {
        int dy = (dys >> (4 * a)) & 15;
        for (int bx = 0; bx < nx; ++bx) {
            int dx = (dxs >> (4 * bx)) & 15;
            int tapoff = (dy * Wpin + dx) * Cin;
            const short* wblk = wt + (size_t)(a * nx + bx) * Mp * Cin;
            for (int cc = 0; cc < Cin; cc += 64) {
                __syncthreads();
                if (BM == 16) {
                    if (wid < 2) gll16(wblk + cc + aoff, AB + (wid << 10));
                } else {
#pragma unroll
                    for (int r = 0; r < BM / 32; ++r)
                        gll16(wblk + cc + aoff + r * 32 * Cin,
                              AB + r * 4096 + (wid << 10));
                }
                gll16(pin + tapoff + cc + pxg[0], BB + (wid << 10));
                gll16(pin + tapoff + cc + pxg[1], BB + 4096 + (wid << 10));
                __syncthreads();
#pragma unroll
                for (int h = 0; h < 2; ++h) {
                    bf16x8 av[FM], bv[FN];
#pragma unroll
                    for (int mf = 0; mf < FM; ++mf)
                        av[mf] = *(const bf16x8*)(AB + rm[mf] * 128 +
                                                  (((h * 4 + cb) ^ (rm[mf] & 7)) << 4));
#pragma unroll
                    for (int nf = 0; nf < FN; ++nf)
                        bv[nf] = *(const bf16x8*)(BB + rn[nf] * 128 +
                                                  (((h * 4 + cb) ^ (rn[nf] & 7)) << 4));
#pragma unroll
                    for (int mf = 0; mf < FM; ++mf)
#pragma unroll
                        for (int nf = 0; nf < FN; ++nf)
                            acc[mf][nf] = __builtin_amdgcn_mfma_f32_16x16x32_bf16(
                                av[mf], bv[nf], acc[mf][nf], 0, 0, 0);
                }
            }
        }
    }

    // epilogue: D row = co = (lane>>4)*4+reg, col = pixel = lane&15
#pragma unroll
    for (int mf = 0; mf < FM; ++mf) {
#pragma unroll
        for (int nf = 0; nf < FN; ++nf) {
            int p = n0 + wn * NSPAN + nf * 16 + (lane & 15);
            int b = p / HuWv, r = p % HuWv;
            int u = r / Wv, v = r % Wv;
            int y = sy * u + py, x = sy * v + px;
            int cobase = m0 + wm * WM + mf * 16 + (lane >> 4) * 4;
            f32x4 vv = acc[mf][nf];
            if (OUTM == 0) {
#pragma unroll
                for (int reg = 0; reg < 4; ++reg) {
                    int co = cobase + reg;
                    if (co < Cout) {
                        float f = vv[reg];
                        if (ACT == 0) f = f > 0.f ? f : 0.f;
                        else f = tanhf(f);
                        outf[((size_t)(b * Cout + co) * Ho + y) * Wo + x] = f;
                    }
                }
            } else {
                s16x4 pk;
#pragma unroll
                for (int reg = 0; reg < 4; ++reg) {
                    float f = vv[reg];
                    f = f > 0.f ? f : 0.f;
                    pk[reg] = f2bf(f);
                }
                *(s16x4*)(outb + (((size_t)b * Hop + y + poff) * Wop + (x + poff)) * Cout +
                          cobase) = pk;
            }
        }
    }
}

// ---------------------------------------------------------------------------

static void launch_fusion(const float* feat, const float* kv, const float* kh,
                          const float* m, float* out, int B, int C, int H, int W,
                          hipStream_t s) {
    int total = B * C * H * (W >> 2);
    fusion4_kernel<<<CDIV(total, 256), 256, 0, s>>>(feat, kv, kh, m, out, B, C, H, W,
                                                    total);
}

extern "C" void kernel_launch(void* const* d_in, const int* in_sizes, int n_in,
                              void* d_out, int out_size, void* d_ws, size_t ws_size,
                              hipStream_t stream) {
    const float* cont = (const float*)d_in[0];
    const float* w1 = (const float*)d_in[1];
    const float* w2 = (const float*)d_in[2];
    const float* w3 = (const float*)d_in[3];
    const float* w4 = (const float*)d_in[4];
    const float* w5 = (const float*)d_in[5];
    const float* w6 = (const float*)d_in[6];
    const float* kv0 = (const float*)d_in[7];
    const float* kh0 = (const float*)d_in[8];
    const float* m0 = (const float*)d_in[9];
    const float* kv1 = (const float*)d_in[10];
    const float* kh1 = (const float*)d_in[11];
    const float* m1 = (const float*)d_in[12];
    const float* kv2 = (const float*)d_in[13];
    const float* kh2 = (const float*)d_in[14];
    const float* m2 = (const float*)d_in[15];
    const float* kv3 = (const float*)d_in[16];
    const float* kh3 = (const float*)d_in[17];
    const float* m3 = (const float*)d_in[18];

    float* out = (float*)d_out;
    float* OUT0 = out;
    float* F8 = out + 1572864;
    float* F16 = out + 2097152;
    float* F32 = out + 18874368;

    // ws: [WT 4MB][A 69.2MB][B 34.6MB] = 108 MB
    float* ws = (float*)d_ws;
    short* WT = (short*)ws;
    float* Areg = ws + 1048576;
    float* Breg = Areg + 17305600;

    short* wt1 = WT;                    // 9*512*64   = 294912
    short* wt2 = wt1 + 294912;          // 9*256*512  = 1179648
    short* wt3 = wt2 + 1179648;         // 9*128*256  = 294912
    short* wt4 = wt3 + 294912;          // 9*128*128  = 147456
    short* wt5 = wt4 + 147456;          // 9*64*128   = 73728
    short* wt6 = wt5 + 73728;           // 9*16*64    = 9216

    short* pin1 = (short*)Breg;         // 32*17*17*64
    float* t16 = Areg;                  // 32*512*32*32 fp32
    short* pin2 = (short*)Areg;         // 32*34*34*512
    short* pin3 = (short*)Breg;         // 32*33*33*256
    float* t32b = Areg;                 // 32*128*64*64 fp32
    short* pin4 = (short*)Areg;         // 32*66*66*128
    short* pin5 = (short*)Breg;         // 32*65*65*128
    short* pin6 = (short*)Areg;         // 32*130*130*64
    float* tout = Breg;                 // 32*3*128*128 fp32

    auto wtr = [&](const float* w, short* wt, int Cin, int Cout, int Mp, int stride) {
        int total = 9 * Mp * Cin;
        wtrans_kernel<<<CDIV(total, 256), 256, 0, stream>>>(w, wt, Cin, Cout, Mp,
                                                            stride, total);
    };
    wtr(w1, wt1, 64, 512, 512, 2);
    wtr(w2, wt2, 512, 256, 256, 1);
    wtr(w3, wt3, 256, 128, 128, 2);
    wtr(w4, wt4, 128, 128, 128, 1);
    wtr(w5, wt5, 128, 64, 64, 2);
    wtr(w6, wt6, 64, 3, 16, 1);

    // 1. f8 = fusion(cont_feat) [32,64,16,16]
    launch_fusion(cont, kv0, kh0, m0, F8, 32, 64, 16, 16, stream);

    // 2. pin1 = s2-pad(f8) 17x17x64 ; conv1 -> t16 fp32 NCHW [32,512,32,32]
    {
        int total = 32 * 17 * 17 * 8;
        pad_kernel<2><<<CDIV(total, 256), 256, 0, stream>>>(F8, pin1, 64, 16, 16, 17, 17,
                                                            total);
        dim3 g(32 * 16 * 16 / 64, 512 / 128, 4);
        convt_mfma<128, true, 0, 0><<<g, 256, 0, stream>>>(
            pin1, wt1, t16, nullptr, 17, 17, 64, 512, 512, 32, 32, 16, 16, 0, 0, 0);
    }
    // 3. f16 = fusion(t16) -> d_out
    launch_fusion(t16, kv1, kh1, m1, F16, 32, 512, 32, 32, stream);

    // 4. pin2 = s1-pad(f16) 34x34x512 ; conv2 -> pin3 (bf16 NHWC 33x33x256)
    {
        int total = 32 * 34 * 34 * 64;
        pad_kernel<1><<<CDIV(total, 256), 256, 0, stream>>>(F16, pin2, 512, 32, 32, 34,
                                                            34, total);
        int zt = 32 * 33 * 33 * 32;
        zb_kernel<<<CDIV(zt, 256), 256, 0, stream>>>(pin3, 33, 33, 32, 0, zt);
        dim3 g(32 * 32 * 32 / 64, 256 / 128, 1);
        convt_mfma<128, false, 1, 0><<<g, 256, 0, stream>>>(
            pin2, wt2, nullptr, pin3, 34, 34, 512, 256, 256, 32, 32, 32, 32, 33, 33, 0);
    }
    // 5. conv3(pin3) -> t32b fp32 NCHW [32,128,64,64]
    {
        dim3 g(32 * 32 * 32 / 64, 1, 4);
        convt_mfma<128, true, 0, 0><<<g, 256, 0, stream>>>(
            pin3, wt3, t32b, nullptr, 33, 33, 256, 128, 128, 64, 64, 32, 32, 0, 0, 0);
    }
    // 6. f32 = fusion(t32b) -> d_out
    launch_fusion(t32b, kv2, kh2, m2, F32, 32, 128, 64, 64, stream);

    // 7. pin4 = s1-pad(f32) 66x66x128 ; conv4 -> pin5 (bf16 NHWC 65x65x128)
    {
        int total = 32 * 66 * 66 * 16;
        pad_kernel<1><<<CDIV(total, 256), 256, 0, stream>>>(F32, pin4, 128, 64, 64, 66,
                                                            66, total);
        int zt = 32 * 65 * 65 * 16;
        zb_kernel<<<CDIV(zt, 256), 256, 0, stream>>>(pin5, 65, 65, 16, 0, zt);
        dim3 g(32 * 64 * 64 / 64, 1, 1);
        convt_mfma<128, false, 1, 0><<<g, 256, 0, stream>>>(
            pin4, wt4, nullptr, pin5, 66, 66, 128, 128, 128, 64, 64, 64, 64, 65, 65, 0);
    }
    // 8. conv5(pin5) -> pin6 (bf16 NHWC 130x130x64, +1 offset) ; zero borders
    {
        int zt = 32 * 130 * 130 * 8;
        zb_kernel<<<CDIV(zt, 256), 256, 0, stream>>>(pin6, 130, 130, 8, 1, zt);
        dim3 g(32 * 64 * 64 / 64, 1, 4);
        convt_mfma<64, true, 1, 0><<<g, 256, 0, stream>>>(
            pin5, wt5, nullptr, pin6, 65, 65, 128, 64, 64, 128, 128, 64, 64, 130, 130, 1);
    }
    // 9. conv6(pin6) -> tout fp32 NCHW [32,3,128,128] with tanh
    {
        dim3 g(32 * 128 * 128 / 64, 1, 1);
        convt_mfma<16, false, 0, 1><<<g, 256, 0, stream>>>(
            pin6, wt6, tout, nullptr, 130, 130, 64, 16, 3, 128, 128, 128, 128, 0, 0, 0);
    }
    // 10. out = fusion(tout) -> d_out
    launch_fusion(tout, kv3, kh3, m3, OUT0, 32, 3, 128, 128, stream);
}

// Round 4
// 659.304 us; speedup vs baseline: 51.3462x; 1.1206x over previous
//
#include <hip/hip_runtime.h>
#include <hip/hip_bf16.h>
#include <cmath>

#define CDIV(a, b) (((a) + (b) - 1) / (b))

typedef __attribute__((ext_vector_type(8))) short bf16x8;
typedef __attribute__((ext_vector_type(4))) short s16x4;
typedef __attribute__((ext_vector_type(4))) float f32x4;

__device__ __forceinline__ short f2bf(float f) {
    unsigned u = __float_as_uint(f);
    unsigned r = (u + 0x7fff + ((u >> 16) & 1)) >> 16;
    return (short)r;
}

__device__ __forceinline__ void gll16(const void* g, void* l) {
    __builtin_amdgcn_global_load_lds((const __attribute__((address_space(1))) void*)g,
                                     (__attribute__((address_space(3))) void*)l, 16, 0, 0);
}

// ---------------------------------------------------------------------------
// C-blocked fusion: 4 channels x 4 pixels per thread. Optionally also emits
// the next conv's bf16 NHWC padded input (interior; borders zeroed by zb).
// ---------------------------------------------------------------------------
template <bool WPIN>
__global__ void fusionC_kernel(const float* __restrict__ feat,
                               const float* __restrict__ kv,
                               const float* __restrict__ kh,
                               const float* __restrict__ m,
                               float* __restrict__ out, short* __restrict__ pin,
                               int B, int C, int H, int W, int Hp, int Wp, int po,
                               int total) {
    int idx = blockIdx.x * blockDim.x + threadIdx.x;
    if (idx >= total) return;
    int Wg = W >> 2;
    int C4 = C >> 2;
    int g = idx % Wg;
    int cg = (idx / Wg) % C4;
    int y = (idx / (Wg * C4)) % H;
    int b = idx / (Wg * C4 * H);
    int x0 = g << 2, c0 = cg << 2;
    int HW = H * W;

    int yy[5];
#pragma unroll
    for (int i = 0; i < 5; ++i) {
        int t = y + i - 2;
        yy[i] = t < 0 ? 0 : (t >= H ? H - 1 : t);
    }
    const float* kvb = kv + ((size_t)b * 5 * H + y) * W + x0;
    const float* khb = kh + ((size_t)b * 5 * H + y) * W + x0;
    f32x4 kvv[5], khv[5];
#pragma unroll
    for (int i = 0; i < 5; ++i) {
        kvv[i] = *(const f32x4*)(kvb + (size_t)i * HW);
        khv[i] = *(const f32x4*)(khb + (size_t)i * HW);
    }
    f32x4 m4 = *(const f32x4*)(m + ((size_t)b * H + y) * W + x0);
    bool interior = (g >= 1 && g <= Wg - 2);

    f32x4 bl[4];
#pragma unroll
    for (int cc = 0; cc < 4; ++cc) {
        const float* fp = feat + (size_t)(b * C + c0 + cc) * HW;
        f32x4 acc = (f32x4){0.f, 0.f, 0.f, 0.f};
        f32x4 ctr;
        if (interior) {
#pragma unroll
            for (int i = 0; i < 5; ++i) {
                const float* row = fp + (size_t)yy[i] * W + x0;
                f32x4 Lv = *(const f32x4*)(row - 4);
                f32x4 Cv = *(const f32x4*)(row);
                f32x4 Rv = *(const f32x4*)(row + 4);
                if (i == 2) ctr = Cv;
                float w8[8] = {Lv[2], Lv[3], Cv[0], Cv[1], Cv[2], Cv[3], Rv[0], Rv[1]};
#pragma unroll
                for (int o = 0; o < 4; ++o) {
                    float r = 0.f;
#pragma unroll
                    for (int j = 0; j < 5; ++j) r = fmaf(khv[j][o], w8[o + j], r);
                    acc[o] = fmaf(kvv[i][o], r, acc[o]);
                }
            }
        } else {
#pragma unroll
            for (int o = 0; o < 4; ++o) {
                int x = x0 + o;
                int xx[5];
#pragma unroll
                for (int j = 0; j < 5; ++j) {
                    int u = x + j - 2;
                    xx[j] = u < 0 ? 0 : (u >= W ? W - 1 : u);
                }
                float a = 0.f;
#pragma unroll
                for (int i = 0; i < 5; ++i) {
                    const float* row = fp + (size_t)yy[i] * W;
                    float r = 0.f;
#pragma unroll
                    for (int j = 0; j < 5; ++j) r = fmaf(khv[j][o], row[xx[j]], r);
                    a = fmaf(kvv[i][o], r, a);
                }
                acc[o] = a;
                ctr[o] = fp[(size_t)y * W + x];
            }
        }
#pragma unroll
        for (int o = 0; o < 4; ++o) bl[cc][o] = m4[o] * acc[o] + (1.f - m4[o]) * ctr[o];
        *(f32x4*)(out + (size_t)(b * C + c0 + cc) * HW + (size_t)y * W + x0) = bl[cc];
    }
    if (WPIN) {
        size_t pbase = ((size_t)b * Hp + y + po) * Wp + x0 + po;
#pragma unroll
        for (int o = 0; o < 4; ++o) {
            s16x4 pk = {f2bf(bl[0][o]), f2bf(bl[1][o]), f2bf(bl[2][o]), f2bf(bl[3][o])};
            *(s16x4*)(pin + (pbase + o) * C + c0) = pk;
        }
    }
}

// scalar fusion for tiny C (C=3 final output)
__global__ void fusion4_kernel(const float* __restrict__ feat,
                               const float* __restrict__ kv,
                               const float* __restrict__ kh,
                               const float* __restrict__ m,
                               float* __restrict__ out,
                               int B, int C, int H, int W, int total) {
    int idx = blockIdx.x * blockDim.x + threadIdx.x;
    if (idx >= total) return;
    int Wg = W >> 2;
    int g = idx % Wg;
    int y = (idx / Wg) % H;
    int c = (idx / (Wg * H)) % C;
    int b = idx / (Wg * H * C);
    int x0 = g << 2;
    int HW = H * W;

    const float* fp = feat + (size_t)(b * C + c) * HW;
    int yy[5];
#pragma unroll
    for (int i = 0; i < 5; ++i) {
        int t = y + i - 2;
        yy[i] = t < 0 ? 0 : (t >= H ? H - 1 : t);
    }
    const float* kvb = kv + ((size_t)b * 5 * H + y) * W + x0;
    const float* khb = kh + ((size_t)b * 5 * H + y) * W + x0;

    f32x4 res;
    if (g >= 1 && g <= Wg - 2) {
        f32x4 kvv[5], khv[5];
#pragma unroll
        for (int i = 0; i < 5; ++i) {
            kvv[i] = *(const f32x4*)(kvb + (size_t)i * HW);
            khv[i] = *(const f32x4*)(khb + (size_t)i * HW);
        }
        f32x4 acc = (f32x4){0.f, 0.f, 0.f, 0.f};
#pragma unroll
        for (int i = 0; i < 5; ++i) {
            const float* row = fp + (size_t)yy[i] * W + x0;
            f32x4 Lv = *(const f32x4*)(row - 4);
            f32x4 Cv = *(const f32x4*)(row);
            f32x4 Rv = *(const f32x4*)(row + 4);
            float w8[8] = {Lv[2], Lv[3], Cv[0], Cv[1], Cv[2], Cv[3], Rv[0], Rv[1]};
#pragma unroll
            for (int o = 0; o < 4; ++o) {
                float r = 0.f;
#pragma unroll
                for (int j = 0; j < 5; ++j) r = fmaf(khv[j][o], w8[o + j], r);
                acc[o] = fmaf(kvv[i][o], r, acc[o]);
            }
        }
        res = acc;
    } else {
#pragma unroll
        for (int o = 0; o < 4; ++o) {
            int x = x0 + o;
            int xx[5];
#pragma unroll
            for (int j = 0; j < 5; ++j) {
                int u = x + j - 2;
                xx[j] = u < 0 ? 0 : (u >= W ? W - 1 : u);
            }
            float acc = 0.f;
#pragma unroll
            for (int i = 0; i < 5; ++i) {
                const float* row = fp + (size_t)yy[i] * W;
                float r = 0.f;
#pragma unroll
                for (int j = 0; j < 5; ++j) r = fmaf(khb[(size_t)j * HW + o], row[xx[j]], r);
                acc = fmaf(kvb[(size_t)i * HW + o], r, acc);
            }
            res[o] = acc;
        }
    }
    const float* mp = m + ((size_t)b * H + y) * W + x0;
    f32x4 m4 = *(const f32x4*)mp;
    f32x4 c4 = *(const f32x4*)(fp + (size_t)y * W + x0);
    f32x4 o4;
#pragma unroll
    for (int o = 0; o < 4; ++o) o4[o] = m4[o] * res[o] + (1.f - m4[o]) * c4[o];
    *(f32x4*)(out + ((size_t)(b * C + c) * H + y) * W + x0) = o4;
}

// zero pad borders of NHWC bf16 pin. mode1: all 4 edges; mode0: high edges only.
__global__ void zb_kernel(short* __restrict__ buf, int Hp, int Wp, int C8, int mode,
                          int total) {
    int tid = blockIdx.x * blockDim.x + threadIdx.x;
    if (tid >= total) return;
    int xp = (tid / C8) % Wp;
    int yp = (tid / (C8 * Wp)) % Hp;
    bool border = mode ? (yp == 0 || yp == Hp - 1 || xp == 0 || xp == Wp - 1)
                       : (yp == Hp - 1 || xp == Wp - 1);
    if (border) *(bf16x8*)(buf + (size_t)tid * 8) = (bf16x8)0;
}

// ---------------------------------------------------------------------------
// Weight transform (round-3 verified): wt[t9][m][ci]; s2 packs phase blocks
// {1,2,2,4} at offsets {0,1,3,5}.
// ---------------------------------------------------------------------------
__global__ void wtrans_kernel(const float* __restrict__ w, short* __restrict__ wt,
                              int Cin, int Cout, int Mp, int stride, int total) {
    int tid = blockIdx.x * blockDim.x + threadIdx.x;
    if (tid >= total) return;
    int ci = tid % Cin;
    int mm = (tid / Cin) % Mp;
    int t9 = tid / (Cin * Mp);
    int i, j;
    if (stride == 1) {
        int a = t9 / 3, bb = t9 % 3;
        i = 2 - a; j = 2 - bb;
    } else {
        int py, px, a, bb;
        if (t9 == 0) { py = 0; px = 0; a = 0; bb = 0; }
        else if (t9 < 3) { py = 0; px = 1; a = 0; bb = t9 - 1; }
        else if (t9 < 5) { py = 1; px = 0; a = t9 - 3; bb = 0; }
        else { int tt = t9 - 5; py = 1; px = 1; a = tt >> 1; bb = tt & 1; }
        i = (py == 0) ? 1 : (a == 0 ? 2 : 0);
        j = (px == 0) ? 1 : (bb == 0 ? 2 : 0);
    }
    float v = 0.f;
    if (mm < Cout) v = w[((ci * Cout + mm) * 3 + i) * 3 + j];
    wt[tid] = f2bf(v);
}

// ---------------------------------------------------------------------------
// Implicit-GEMM convT, BM x BN tile, 4 waves, BK=64, XOR-swizzled LDS.
// S2: blockIdx.z = phase. OUTM 0: fp32 NCHW (+relu/tanh). OUTM 1: bf16 NHWC pin.
// ---------------------------------------------------------------------------
template <int BM, int BN, bool S2, int OUTM, int ACT>
__global__ void convt_mfma(const short* __restrict__ pin, const short* __restrict__ wtc,
                           float* __restrict__ outf, short* __restrict__ outb,
                           int Hpin, int Wpin, int Cin, int Mp, int Cout,
                           int Ho, int Wo, int Hu, int Wv,
                           int Hop, int Wop, int poff) {
    constexpr int WAVES_M = (BM >= 128) ? 2 : 1;
    constexpr int WM = BM / WAVES_M;        // <=64
    constexpr int WN = BN / (4 / WAVES_M);
    constexpr int FM = WM / 16, FN = WN / 16;
    constexpr int RB = BN / 32;
    __shared__ __align__(16) short Alds[BM * 64];
    __shared__ __align__(16) short Blds[BN * 64];

    int t = threadIdx.x, lane = t & 63, wid = t >> 6;
    int n0 = blockIdx.x * BN, m0 = blockIdx.y * BM;

    int py = 0, px = 0, ny = 3, nx = 3, dys = 0x210, dxs = 0x210, sy = 1;
    const short* wt = wtc;
    if (S2) {
        int pz = blockIdx.z;
        py = pz >> 1; px = pz & 1;
        ny = 1 + py; nx = 1 + px;
        dys = py ? 0x10 : 0; dxs = px ? 0x10 : 0;
        int pre = (pz == 0) ? 0 : (pz == 1) ? 1 : (pz == 2) ? 3 : 5;
        wt = wtc + (size_t)pre * Mp * Cin;
        sy = 2;
    }

    int rowS = t >> 3;
    int dS = (t & 7) ^ (rowS & 7);
    int HuWv = Hu * Wv;
    int pxg[RB];
#pragma unroll
    for (int rb = 0; rb < RB; ++rb) {
        int n = n0 + rowS + rb * 32;
        int b = n / HuWv, r = n % HuWv;
        int u = r / Wv, v = r % Wv;
        pxg[rb] = ((b * Hpin + u) * Wpin + v) * Cin + dS * 8;
    }
    int aoff = (m0 + rowS) * Cin + dS * 8;

    char* AB = (char*)Alds;
    char* BB = (char*)Blds;

    int wm = (WAVES_M == 2) ? (wid & 1) : 0;
    int wn = (WAVES_M == 2) ? (wid >> 1) : wid;
    int cb = lane >> 4;
    int rm[FM], rn[FN];
#pragma unroll
    for (int mf = 0; mf < FM; ++mf) rm[mf] = wm * WM + mf * 16 + (lane & 15);
#pragma unroll
    for (int nf = 0; nf < FN; ++nf) rn[nf] = wn * WN + nf * 16 + (lane & 15);

    f32x4 acc[FM][FN];
#pragma unroll
    for (int mf = 0; mf < FM; ++mf)
#pragma unroll
        for (int nf = 0; nf < FN; ++nf) acc[mf][nf] = (f32x4){0.f, 0.f, 0.f, 0.f};

    for (int a = 0; a < ny; ++a) {
        int dy = (dys >> (4 * a)) & 15;
        for (int bx = 0; bx < nx; ++bx) {
            int dx = (dxs >> (4 * bx)) & 15;
            int tapoff = (dy * Wpin + dx) * Cin;
            const short* wblk = wt + (size_t)(a * nx + bx) * Mp * Cin;
            for (int cc = 0; cc < Cin; cc += 64) {
                __syncthreads();
                if (BM >= 32) {
#pragma unroll
                    for (int r = 0; r < BM / 32; ++r)
                        gll16(wblk + cc + aoff + r * 32 * Cin,
                              AB + r * 4096 + (wid << 10));
                } else {
                    if (wid < BM / 8) gll16(wblk + cc + aoff, AB + (wid << 10));
                }
#pragma unroll
                for (int rb = 0; rb < RB; ++rb)
                    gll16(pin + tapoff + cc + pxg[rb], BB + rb * 4096 + (wid << 10));
                __syncthreads();
#pragma unroll
                for (int h = 0; h < 2; ++h) {
                    bf16x8 av[FM], bv[FN];
#pragma unroll
                    for (int mf = 0; mf < FM; ++mf)
                        av[mf] = *(const bf16x8*)(AB + rm[mf] * 128 +
                                                  (((h * 4 + cb) ^ (rm[mf] & 7)) << 4));
#pragma unroll
                    for (int nf = 0; nf < FN; ++nf)
                        bv[nf] = *(const bf16x8*)(BB + rn[nf] * 128 +
                                                  (((h * 4 + cb) ^ (rn[nf] & 7)) << 4));
#pragma unroll
                    for (int mf = 0; mf < FM; ++mf)
#pragma unroll
                        for (int nf = 0; nf < FN; ++nf)
                            acc[mf][nf] = __builtin_amdgcn_mfma_f32_16x16x32_bf16(
                                av[mf], bv[nf], acc[mf][nf], 0, 0, 0);
                }
            }
        }
    }

#pragma unroll
    for (int mf = 0; mf < FM; ++mf) {
#pragma unroll
        for (int nf = 0; nf < FN; ++nf) {
            int p = n0 + wn * WN + nf * 16 + (lane & 15);
            int b = p / HuWv, r = p % HuWv;
            int u = r / Wv, v = r % Wv;
            int y = sy * u + py, x = sy * v + px;
            int cobase = m0 + wm * WM + mf * 16 + (lane >> 4) * 4;
            f32x4 vv = acc[mf][nf];
            if (OUTM == 0) {
#pragma unroll
                for (int reg = 0; reg < 4; ++reg) {
                    int co = cobase + reg;
                    if (co < Cout) {
                        float f = vv[reg];
                        if (ACT == 0) f = f > 0.f ? f : 0.f;
                        else f = tanhf(f);
                        outf[((size_t)(b * Cout + co) * Ho + y) * Wo + x] = f;
                    }
                }
            } else {
                s16x4 pk;
#pragma unroll
                for (int reg = 0; reg < 4; ++reg) {
                    float f = vv[reg];
                    f = f > 0.f ? f : 0.f;
                    pk[reg] = f2bf(f);
                }
                *(s16x4*)(outb + (((size_t)b * Hop + y + poff) * Wop + (x + poff)) * Cout +
                          cobase) = pk;
            }
        }
    }
}

// ---------------------------------------------------------------------------

extern "C" void kernel_launch(void* const* d_in, const int* in_sizes, int n_in,
                              void* d_out, int out_size, void* d_ws, size_t ws_size,
                              hipStream_t stream) {
    const float* cont = (const float*)d_in[0];
    const float* w1 = (const float*)d_in[1];
    const float* w2 = (const float*)d_in[2];
    const float* w3 = (const float*)d_in[3];
    const float* w4 = (const float*)d_in[4];
    const float* w5 = (const float*)d_in[5];
    const float* w6 = (const float*)d_in[6];
    const float* kv0 = (const float*)d_in[7];
    const float* kh0 = (const float*)d_in[8];
    const float* m0 = (const float*)d_in[9];
    const float* kv1 = (const float*)d_in[10];
    const float* kh1 = (const float*)d_in[11];
    const float* m1 = (const float*)d_in[12];
    const float* kv2 = (const float*)d_in[13];
    const float* kh2 = (const float*)d_in[14];
    const float* m2 = (const float*)d_in[15];
    const float* kv3 = (const float*)d_in[16];
    const float* kh3 = (const float*)d_in[17];
    const float* m3 = (const float*)d_in[18];

    float* out = (float*)d_out;
    float* OUT0 = out;
    float* F8 = out + 1572864;
    float* F16 = out + 2097152;
    float* F32 = out + 18874368;

    const size_t MiB = 1 << 20;
    char* wsb = (char*)d_ws;
    short* WT = (short*)wsb;                       // [0,4)MiB
    float* t16 = (float*)(wsb + 4 * MiB);          // [4,68)
    short* pin2 = (short*)(wsb + 68 * MiB);        // [68,104.2)
    short* pin3 = (short*)(wsb + 4 * MiB);         // [4,21.1)   (t16 dead)
    float* t32b = (float*)(wsb + 22 * MiB);        // [22,86)
    short* pin4 = (short*)(wsb + 88 * MiB);        // [88,122)
    short* pin5 = (short*)(wsb + 4 * MiB);         // [4,37.1)   (t32b dead)
    short* pin6 = (short*)(wsb + 38 * MiB);        // [38,104.1) (pin4 dead after conv4... dead after conv5 issues; disjoint regions anyway)
    float* tout = (float*)(wsb + 106 * MiB);       // [106,112)
    short* pin1 = (short*)(wsb + 112 * MiB);       // [112,113.2)

    short* wt1 = WT;                    // 9*512*64
    short* wt2 = wt1 + 294912;          // 9*256*512
    short* wt3 = wt2 + 1179648;         // 9*128*256
    short* wt4 = wt3 + 294912;          // 9*128*128
    short* wt5 = wt4 + 147456;          // 9*64*128
    short* wt6 = wt5 + 73728;           // 9*16*64

    auto wtr = [&](const float* w, short* wt, int Cin, int Cout, int Mp, int stride) {
        int total = 9 * Mp * Cin;
        wtrans_kernel<<<CDIV(total, 256), 256, 0, stream>>>(w, wt, Cin, Cout, Mp,
                                                            stride, total);
    };
    wtr(w1, wt1, 64, 512, 512, 2);
    wtr(w2, wt2, 512, 256, 256, 1);
    wtr(w3, wt3, 256, 128, 128, 2);
    wtr(w4, wt4, 128, 128, 128, 1);
    wtr(w5, wt5, 128, 64, 64, 2);
    wtr(w6, wt6, 64, 3, 16, 1);

    auto zb = [&](short* buf, int Hp, int Wp, int C8, int mode) {
        int zt = 32 * Hp * Wp * C8;
        zb_kernel<<<CDIV(zt, 256), 256, 0, stream>>>(buf, Hp, Wp, C8, mode, zt);
    };
    auto fusC = [&](const float* feat, const float* kv, const float* kh, const float* m,
                    float* o, short* pin, int C, int H, int W, int Hp, int Wp, int po) {
        int total = 32 * H * (C >> 2) * (W >> 2);
        fusionC_kernel<true><<<CDIV(total, 256), 256, 0, stream>>>(
            feat, kv, kh, m, o, pin, 32, C, H, W, Hp, Wp, po, total);
    };

    // 1. f8 = fusion(cont) -> F8 + pin1 (17x17x64, po=0)
    zb(pin1, 17, 17, 8, 0);
    fusC(cont, kv0, kh0, m0, F8, pin1, 64, 16, 16, 17, 17, 0);

    // 2. conv1 (s2): pin1 -> t16 fp32 [32,512,32,32]
    {
        dim3 g(32 * 16 * 16 / 128, 512 / 128, 4);
        convt_mfma<128, 128, true, 0, 0><<<g, 256, 0, stream>>>(
            pin1, wt1, t16, nullptr, 17, 17, 64, 512, 512, 32, 32, 16, 16, 0, 0, 0);
    }
    // 3. f16 = fusion(t16) -> F16 + pin2 (34x34x512, po=1)
    zb(pin2, 34, 34, 64, 1);
    fusC(t16, kv1, kh1, m1, F16, pin2, 512, 32, 32, 34, 34, 1);

    // 4. conv2 (s1): pin2 -> pin3 (33x33x256)
    zb(pin3, 33, 33, 32, 0);
    {
        dim3 g(32 * 32 * 32 / 128, 256 / 128, 1);
        convt_mfma<128, 128, false, 1, 0><<<g, 256, 0, stream>>>(
            pin2, wt2, nullptr, pin3, 34, 34, 512, 256, 256, 32, 32, 32, 32, 33, 33, 0);
    }
    // 5. conv3 (s2): pin3 -> t32b fp32 [32,128,64,64]
    {
        dim3 g(32 * 32 * 32 / 128, 1, 4);
        convt_mfma<128, 128, true, 0, 0><<<g, 256, 0, stream>>>(
            pin3, wt3, t32b, nullptr, 33, 33, 256, 128, 128, 64, 64, 32, 32, 0, 0, 0);
    }
    // 6. f32 = fusion(t32b) -> F32 + pin4 (66x66x128, po=1)
    zb(pin4, 66, 66, 16, 1);
    fusC(t32b, kv2, kh2, m2, F32, pin4, 128, 64, 64, 66, 66, 1);

    // 7. conv4 (s1): pin4 -> pin5 (65x65x128)
    zb(pin5, 65, 65, 16, 0);
    {
        dim3 g(32 * 64 * 64 / 128, 1, 1);
        convt_mfma<128, 128, false, 1, 0><<<g, 256, 0, stream>>>(
            pin4, wt4, nullptr, pin5, 66, 66, 128, 128, 128, 64, 64, 64, 64, 65, 65, 0);
    }
    // 8. conv5 (s2): pin5 -> pin6 (130x130x64, poff=1)
    zb(pin6, 130, 130, 8, 1);
    {
        dim3 g(32 * 64 * 64 / 128, 1, 4);
        convt_mfma<64, 128, true, 1, 0><<<g, 256, 0, stream>>>(
            pin5, wt5, nullptr, pin6, 65, 65, 128, 64, 64, 128, 128, 64, 64, 130, 130, 1);
    }
    // 9. conv6 (s1): pin6 -> tout fp32 [32,3,128,128] tanh
    {
        dim3 g(32 * 128 * 128 / 64, 1, 1);
        convt_mfma<16, 64, false, 0, 1><<<g, 256, 0, stream>>>(
            pin6, wt6, tout, nullptr, 130, 130, 64, 16, 3, 128, 128, 128, 128, 0, 0, 0);
    }
    // 10. out = fusion(tout) -> OUT0 (C=3 scalar path)
    {
        int total = 32 * 3 * 128 * (128 >> 2);
        fusion4_kernel<<<CDIV(total, 256), 256, 0, stream>>>(tout, kv3, kh3, m3, OUT0,
                                                             32, 3, 128, 128, total);
    }
}